// Round 1
// baseline (66.361 us; speedup 1.0000x reference)
//
#include <hip/hip_runtime.h>

// HONU order-2, L=64: out[i] = b + sum_{j<=k} W[woff(j)+k-j] * x[i,j] * x[i,k]
// woff(j) = 64j - j(j-1)/2  (lex order of combinations_with_replacement)
//
// Layout: 256 blocks x 256 threads. Block owns 64 rows (lane = row).
// The 4 waves of a block split the j-range with a compile-time balanced
// pairing (exactly 520 FMAs per wave); W indices are compile-time constants
// inside each wave-uniform branch -> scalar s_load batches, FMA uses the
// SGPR operand slot. x row lives in 64 VGPRs (fully unrolled indexing).

template <int J0, int J1>
__device__ __forceinline__ void accum_range(const float* __restrict__ W,
                                            const float (&x)[64],
                                            float& acc) {
#pragma unroll
  for (int j = J0; j < J1; ++j) {
    const int base = j * 64 - (j * (j - 1)) / 2;  // woff(j), compile-time
    float y = 0.0f;
#pragma unroll
    for (int k = j; k < 64; ++k) {
      y = __builtin_fmaf(W[base + (k - j)], x[k], y);
    }
    acc = __builtin_fmaf(x[j], y, acc);
  }
}

__global__ __launch_bounds__(256) void honu_kernel(
    const float* __restrict__ X, const float* __restrict__ W,
    const float* __restrict__ Bias, float* __restrict__ out, int nrows) {
  __shared__ float part[4][64];

  const int tid = threadIdx.x;
  const int lane = tid & 63;
  const int wave = __builtin_amdgcn_readfirstlane(tid >> 6);
  const int row = blockIdx.x * 64 + lane;

  // Load this row's 64 floats into registers (16 x float4, 16B aligned).
  float x[64];
  if (row < nrows) {
    const float4* xp = reinterpret_cast<const float4*>(X + (size_t)row * 64);
#pragma unroll
    for (int q = 0; q < 16; ++q) {
      float4 v = xp[q];
      x[4 * q + 0] = v.x;
      x[4 * q + 1] = v.y;
      x[4 * q + 2] = v.z;
      x[4 * q + 3] = v.w;
    }
  } else {
#pragma unroll
    for (int q = 0; q < 64; ++q) x[q] = 0.0f;
  }

  float acc = 0.0f;
  // Balanced contiguous pairing: wave s takes j in [8s,8s+8) U [56-8s,64-8s)
  // -> 520 FMAs each. Branch condition is wave-uniform (readfirstlane).
  if (wave == 0) {
    accum_range<0, 8>(W, x, acc);
    accum_range<56, 64>(W, x, acc);
  } else if (wave == 1) {
    accum_range<8, 16>(W, x, acc);
    accum_range<48, 56>(W, x, acc);
  } else if (wave == 2) {
    accum_range<16, 24>(W, x, acc);
    accum_range<40, 48>(W, x, acc);
  } else {
    accum_range<24, 40>(W, x, acc);
  }

  part[wave][lane] = acc;
  __syncthreads();

  if (tid < 64) {
    const int orow = blockIdx.x * 64 + tid;
    if (orow < nrows) {
      float r = part[0][tid] + part[1][tid] + part[2][tid] + part[3][tid] +
                Bias[0];
      out[orow] = r;
    }
  }
}

extern "C" void kernel_launch(void* const* d_in, const int* in_sizes, int n_in,
                              void* d_out, int out_size, void* d_ws,
                              size_t ws_size, hipStream_t stream) {
  const float* X = (const float*)d_in[0];     // (16384, 64) fp32
  const float* W = (const float*)d_in[1];     // (2145,) fp32 (first 2080 used)
  const float* Bias = (const float*)d_in[2];  // (1,) fp32
  float* out = (float*)d_out;                 // (16384,) fp32

  const int nrows = out_size;  // 16384
  const int grid = (nrows + 63) / 64;
  honu_kernel<<<grid, 256, 0, stream>>>(X, W, Bias, out, nrows);
}

// Round 2
// 60.077 us; speedup vs baseline: 1.1046x; 1.1046x over previous
//
#include <hip/hip_runtime.h>

// HONU order-2, L=64: out[i] = b + sum_{j<=k} W[woff(j)+k-j] * x[i,j] * x[i,k]
// woff(j) = 64j - j(j-1)/2  (lex order of combinations_with_replacement)
//
// R2 layout: 256 blocks x 1024 threads (16 waves = 4 waves/SIMD for latency
// hiding). Block owns 64 rows (lane = row). X-tile staged via LDS:
// global loads are perfectly coalesced (1 float4/thread), LDS row stride 65
// keeps every access at <=2 lanes/bank (free on CDNA4). The 16 waves split
// the triangular j-range with a compile-time balanced pairing
// (wave s: j in {2s,2s+1} U {62-2s,63-2s} -> exactly 134 FMAs each), so all
// W indices are compile-time constants -> uniform scalar loads.

#define ROWS 64
#define XSTRIDE 65  // +1 pad: LDS bank = (65*lane + k)%32 = (lane+k)%32 -> 2-way, free

template <int J0, int J1>
__device__ __forceinline__ void accum_range(const float* __restrict__ W,
                                            const float (&x)[64],
                                            float& acc) {
#pragma unroll
  for (int j = J0; j < J1; ++j) {
    const int base = j * 64 - (j * (j - 1)) / 2;  // woff(j), compile-time
    float y = 0.0f;
#pragma unroll
    for (int k = j; k < 64; ++k) {
      y = __builtin_fmaf(W[base + (k - j)], x[k], y);
    }
    acc = __builtin_fmaf(x[j], y, acc);
  }
}

template <int S>
__device__ __forceinline__ float wave_work(const float* __restrict__ W,
                                           const float* __restrict__ xrow) {
  // Wave S needs only x[2S..63] (its smallest j is 2S).
  float x[64];
#pragma unroll
  for (int k = 2 * S; k < 64; ++k) x[k] = xrow[k];
  float acc = 0.0f;
  accum_range<2 * S, 2 * S + 2>(W, x, acc);
  accum_range<62 - 2 * S, 64 - 2 * S>(W, x, acc);
  return acc;
}

__global__ __launch_bounds__(1024, 4) void honu_kernel(
    const float* __restrict__ X, const float* __restrict__ W,
    const float* __restrict__ Bias, float* __restrict__ out, int nrows) {
  __shared__ float tile[ROWS * XSTRIDE];  // 16.6 KB
  __shared__ float part[16][64];          // 4 KB

  const int tid = threadIdx.x;
  const int lane = tid & 63;
  const int wave = tid >> 6;
  const int row0 = blockIdx.x * ROWS;

  // Coalesced staging: thread tid loads float4 #tid of the 64x64 tile.
  {
    const int r = tid >> 4;         // row within tile
    const int c = (tid & 15) << 2;  // starting col
    float4 v = make_float4(0.f, 0.f, 0.f, 0.f);
    if (row0 + r < nrows) {
      v = reinterpret_cast<const float4*>(X)[(size_t)(row0 + r) * 16 +
                                             (tid & 15)];
    }
    float* dst = &tile[r * XSTRIDE + c];
    dst[0] = v.x;
    dst[1] = v.y;
    dst[2] = v.z;
    dst[3] = v.w;
  }
  __syncthreads();

  const float* xrow = &tile[lane * XSTRIDE];
  float acc = 0.0f;
  switch (wave) {  // wave-uniform branch
    case 0:  acc = wave_work<0>(W, xrow);  break;
    case 1:  acc = wave_work<1>(W, xrow);  break;
    case 2:  acc = wave_work<2>(W, xrow);  break;
    case 3:  acc = wave_work<3>(W, xrow);  break;
    case 4:  acc = wave_work<4>(W, xrow);  break;
    case 5:  acc = wave_work<5>(W, xrow);  break;
    case 6:  acc = wave_work<6>(W, xrow);  break;
    case 7:  acc = wave_work<7>(W, xrow);  break;
    case 8:  acc = wave_work<8>(W, xrow);  break;
    case 9:  acc = wave_work<9>(W, xrow);  break;
    case 10: acc = wave_work<10>(W, xrow); break;
    case 11: acc = wave_work<11>(W, xrow); break;
    case 12: acc = wave_work<12>(W, xrow); break;
    case 13: acc = wave_work<13>(W, xrow); break;
    case 14: acc = wave_work<14>(W, xrow); break;
    default: acc = wave_work<15>(W, xrow); break;
  }
  part[wave][lane] = acc;
  __syncthreads();

  if (tid < 64) {
    const int orow = row0 + tid;
    if (orow < nrows) {
      float r = Bias[0];
#pragma unroll
      for (int w = 0; w < 16; ++w) r += part[w][tid];
      out[orow] = r;
    }
  }
}

extern "C" void kernel_launch(void* const* d_in, const int* in_sizes, int n_in,
                              void* d_out, int out_size, void* d_ws,
                              size_t ws_size, hipStream_t stream) {
  const float* X = (const float*)d_in[0];     // (16384, 64) fp32
  const float* W = (const float*)d_in[1];     // (2145,) fp32 (first 2080 used)
  const float* Bias = (const float*)d_in[2];  // (1,) fp32
  float* out = (float*)d_out;                 // (16384,) fp32

  const int nrows = out_size;  // 16384
  const int grid = (nrows + ROWS - 1) / ROWS;
  honu_kernel<<<grid, 1024, 0, stream>>>(X, W, Bias, out, nrows);
}